// Round 6
// baseline (398.873 us; speedup 1.0000x reference)
//
#include <hip/hip_runtime.h>
#include <math.h>

// ---------------------------------------------------------------------------
// TransformerBlock: B=2, T=2048, D=1024, H=16, HD=64, pre-LN, causal attn, GELU
// Round 6: GEMMs restructured as producer/consumer wave pipeline — 4 compute
// waves + 1 staging wave, 3-slot LDS ring, flag sync via LDS, fine-grained
// s_waitcnt vmcnt(2*IPT) (never 0), NO __syncthreads in the K-loop. This is
// the documented path past the barrier-drain plateau (loads stay in flight
// across tile boundaries). Attention/LN unchanged from round 5.
// ---------------------------------------------------------------------------

typedef _Float16 half8 __attribute__((ext_vector_type(8)));
typedef _Float16 half4v __attribute__((ext_vector_type(4)));
typedef float floatx4 __attribute__((ext_vector_type(4)));

#define DMODEL 1024
#define SEQT   2048
#define NTOK   4096   // B*T
#define NHEAD  16
#define HDIM   64

// Async global->LDS, 16B/lane. LDS dest = wave-uniform base + lane*16 [m104].
__device__ __forceinline__ void llds16(const _Float16* g, _Float16* l) {
  __builtin_amdgcn_global_load_lds(
      (const __attribute__((address_space(1))) void*)g,
      (__attribute__((address_space(3))) void*)l, 16, 0, 0);
}

// s_waitcnt immediates: vmcnt[3:0]|[15:14], expcnt[6:4]=7, lgkmcnt[11:8]
#define WAITCNT_VM(n)  ((n & 15) | ((n >> 4) << 14) | 0x0F70)
#define WAITCNT_LGKM0  (0xC07F)   // lgkmcnt(0), vmcnt/expcnt ignored

// ---------------------------------------------------------------------------
// Weight convert+transpose: fp32 [K,N] -> f16 [N,K].
// wt layout (elements): Wq^T @0, Wk^T @1M, Wv^T @2M, Wo^T @3M, W1^T @4M (4096x1024),
//                       W2^T @8M (1024x4096). Total 12M halves = 24MB.
// ---------------------------------------------------------------------------
__global__ __launch_bounds__(256) void wtrans_kernel(
    const float* __restrict__ Wq, const float* __restrict__ Wk,
    const float* __restrict__ Wv, const float* __restrict__ Wo,
    const float* __restrict__ W1, const float* __restrict__ W2,
    _Float16* __restrict__ wt_base) {
  __shared__ float tilebuf[32][33];
  int id = blockIdx.x;
  const float* src; _Float16* dst; int K, N, t;
  if (id < 4096) {
    int s = id >> 10;
    src = (s == 0) ? Wq : (s == 1) ? Wk : (s == 2) ? Wv : Wo;
    dst = wt_base + (size_t)s * (1024 * 1024);
    K = 1024; N = 1024; t = id & 1023;
  } else if (id < 8192) {
    src = W1; dst = wt_base + (size_t)4 * 1024 * 1024; K = 1024; N = 4096; t = id - 4096;
  } else {
    src = W2; dst = wt_base + (size_t)8 * 1024 * 1024; K = 4096; N = 1024; t = id - 8192;
  }
  int tilesN = N >> 5;
  int tk = t / tilesN, tn = t % tilesN;
  int c = threadIdx.x & 31, r0 = threadIdx.x >> 5;
#pragma unroll
  for (int i = 0; i < 4; ++i) {
    int r = r0 + i * 8;
    tilebuf[r][c] = src[(size_t)(tk * 32 + r) * N + tn * 32 + c];
  }
  __syncthreads();
#pragma unroll
  for (int i = 0; i < 4; ++i) {
    int r = r0 + i * 8;
    dst[(size_t)(tn * 32 + r) * K + tk * 32 + c] = (_Float16)tilebuf[c][r];
  }
}

// ---------------------------------------------------------------------------
// LayerNorm: fp32 in -> f16 out. One row (D=1024) per 256-thread block.
// ---------------------------------------------------------------------------
__global__ __launch_bounds__(256) void ln_kernel(
    const float* __restrict__ x, const float* __restrict__ g,
    const float* __restrict__ b, _Float16* __restrict__ out) {
  int row = blockIdx.x;
  int t = threadIdx.x;
  const float4 xv = ((const float4*)(x + (size_t)row * DMODEL))[t];
  float s = xv.x + xv.y + xv.z + xv.w;
  float s2 = xv.x * xv.x + xv.y * xv.y + xv.z * xv.z + xv.w * xv.w;
#pragma unroll
  for (int off = 32; off; off >>= 1) {
    s += __shfl_down(s, off);
    s2 += __shfl_down(s2, off);
  }
  __shared__ float red[8];
  int wid = t >> 6;
  if ((t & 63) == 0) { red[wid] = s; red[wid + 4] = s2; }
  __syncthreads();
  s = red[0] + red[1] + red[2] + red[3];
  s2 = red[4] + red[5] + red[6] + red[7];
  float mu = s * (1.0f / DMODEL);
  float var = s2 * (1.0f / DMODEL) - mu * mu;
  float rstd = rsqrtf(var + 1e-5f);
  const float4 gv = ((const float4*)g)[t];
  const float4 bv = ((const float4*)b)[t];
  half4v o;
  o[0] = (_Float16)((xv.x - mu) * rstd * gv.x + bv.x);
  o[1] = (_Float16)((xv.y - mu) * rstd * gv.y + bv.y);
  o[2] = (_Float16)((xv.z - mu) * rstd * gv.z + bv.z);
  o[3] = (_Float16)((xv.w - mu) * rstd * gv.w + bv.w);
  *(half4v*)(out + (size_t)row * DMODEL + t * 4) = o;
}

// ---------------------------------------------------------------------------
// f16 MFMA GEMM, producer-consumer pipeline. C[4096,N] = A[4096,K] @ B
// (B as Bt[N,K] f16). M-tile 128, N-tile 128 (MODE 0/2) or 64 (MODE 1).
// 320 threads: waves 0-3 compute (64x64 or 32x64 each), wave 4 stages tiles
// into a 3-slot LDS ring with global_load_lds and publishes progress via LDS
// flags. No __syncthreads in the K-loop; producer waits vmcnt(2*IPT) only.
// MODE 0: QKV fused; q,k scatter [B,H,T,HD]; v scatters TRANSPOSED [B,H,HD,T]
// MODE 1: bias + residual(fp32) add; fp32 output, row stride 1024
// MODE 2: bias + fast GELU; f16 output, row stride 4096
// ---------------------------------------------------------------------------
template <int MODE>
__global__ __launch_bounds__(320) void gemm_kernel(
    const _Float16* __restrict__ A, const _Float16* __restrict__ Bt0, int K,
    const float* __restrict__ bias0, const float* __restrict__ bias1,
    const float* __restrict__ bias2, const float* __restrict__ res,
    float* __restrict__ outf, _Float16* __restrict__ outh) {
  constexpr int NT = (MODE == 1) ? 64 : 128;   // N-tile
  constexpr int MI = (NT == 128) ? 4 : 2;      // A-frag rows per wave
  constexpr int NSTAGE = 3;
  constexpr int ACH = 8;                       // producer insts for A tile
  constexpr int BCH = NT / 16;                 // producer insts for B tile
  constexpr int IPT = ACH + BCH;               // loads per tile
  __shared__ __align__(16) _Float16 As[NSTAGE][128 * 32];
  __shared__ __align__(16) _Float16 Bs[NSTAGE][NT * 32];
  __shared__ int ready_f, done_f;
  const int tid = threadIdx.x;
  const int w = tid >> 6, lane = tid & 63;
  const int m0 = blockIdx.x * 128;
  const _Float16* Bt;
  const float* bias;
  _Float16* outh_sel = outh;
  int n0, sel = 0;
  if (MODE == 0) {
    sel = blockIdx.y >> 3;
    n0 = (blockIdx.y & 7) * 128;
    Bt = Bt0 + (size_t)sel * (1024 * 1024);
    bias = (sel == 0) ? bias0 : (sel == 1) ? bias1 : bias2;
    outh_sel = outh + (size_t)sel * ((size_t)NTOK * DMODEL);
  } else {
    n0 = blockIdx.y * NT;
    Bt = Bt0;
    bias = bias0;
  }
  if (tid == 0) { ready_f = 0; done_f = 0; }
  __syncthreads();  // flags visible; no loads outstanding yet
  volatile int* rv = &ready_f;
  volatile int* dv = &done_f;
  const int nk = K >> 5;

  if (w == 4) {
    // ---------------- producer wave ----------------
    const int r4 = lane >> 2, c8 = (lane & 3) * 8;
    const _Float16* gA = A + (size_t)(m0 + r4) * K + c8;
    const _Float16* gB = Bt + (size_t)(n0 + r4) * K + c8;
    for (int t = 0; t < nk; ++t) {
      if (t >= NSTAGE) {
        const int need = 4 * (t - NSTAGE + 1);
        while (*dv < need) {}
      }
      const int slot = t % NSTAGE;
      _Float16* la = &As[slot][0];
      _Float16* lb = &Bs[slot][0];
#pragma unroll
      for (int i = 0; i < ACH; ++i)
        llds16(gA + (size_t)(i * 16) * K, la + i * 512);
#pragma unroll
      for (int i = 0; i < BCH; ++i)
        llds16(gB + (size_t)(i * 16) * K, lb + i * 512);
      gA += 32; gB += 32;
      if (t >= 2) {
        __builtin_amdgcn_s_waitcnt(WAITCNT_VM(2 * IPT));  // tiles <= t-2 landed
        if (lane == 0) *rv = t - 1;                        // tiles 0..t-2 ready
      }
    }
    __builtin_amdgcn_s_waitcnt(WAITCNT_VM(0));
    if (lane == 0) *rv = nk;
    return;
  }

  // ---------------- consumer waves (0-3) ----------------
  const int l15 = lane & 15, q8 = lane >> 4;
  const int wrow = (NT == 128) ? (w >> 1) * 64 : w * 32;
  const int wcol = (NT == 128) ? (w & 1) * 64 : 0;

  floatx4 acc[MI][4];
#pragma unroll
  for (int i = 0; i < MI; ++i)
#pragma unroll
    for (int j = 0; j < 4; ++j) acc[i][j] = (floatx4){0.f, 0.f, 0.f, 0.f};

  for (int t = 0; t < nk; ++t) {
    while (*rv < t + 1) {}   // broadcast LDS read, exits together
    const int slot = t % NSTAGE;
    const _Float16* as = &As[slot][0];
    const _Float16* bs = &Bs[slot][0];
    half8 af[MI], bf[4];
#pragma unroll
    for (int i = 0; i < MI; ++i)
      af[i] = *(const half8*)&as[(wrow + i * 16 + l15) * 32 + q8 * 8];
#pragma unroll
    for (int j = 0; j < 4; ++j)
      bf[j] = *(const half8*)&bs[(wcol + j * 16 + l15) * 32 + q8 * 8];
    __builtin_amdgcn_sched_barrier(0);            // pin reads before the wait
    __builtin_amdgcn_s_waitcnt(WAITCNT_LGKM0);    // frags in VGPRs
    if (lane == 0) atomicAdd(&done_f, 1);         // release slot
#pragma unroll
    for (int i = 0; i < MI; ++i)
#pragma unroll
      for (int j = 0; j < 4; ++j)
        acc[i][j] = __builtin_amdgcn_mfma_f32_16x16x32_f16(af[i], bf[j], acc[i][j], 0, 0, 0);
  }

  // Epilogue. C/D layout: col = lane&15, row = (lane>>4)*4 + reg   [m89/m91]
#pragma unroll
  for (int i = 0; i < MI; ++i) {
    int rowb = m0 + wrow + i * 16 + q8 * 4;
#pragma unroll
    for (int j = 0; j < 4; ++j) {
      int col = n0 + wcol + j * 16 + l15;
      float bval = bias[col];
#pragma unroll
      for (int r = 0; r < 4; ++r) {
        int row = rowb + r;
        float v = acc[i][j][r] + bval;
        if (MODE == 0) {
          int bb = row >> 11, tt = row & 2047;
          int hh = col >> 6, hd = col & 63;
          if (sel == 2)  // V transposed: [B,H,HD,T] so attention PV needs no LDS transpose
            outh_sel[((size_t)(bb * NHEAD + hh) * HDIM + hd) * SEQT + tt] = (_Float16)v;
          else
            outh_sel[((size_t)(bb * NHEAD + hh) * SEQT + tt) * HDIM + hd] = (_Float16)v;
        } else if (MODE == 1) {
          v += res[(size_t)row * 1024 + col];
          outf[(size_t)row * 1024 + col] = v;
        } else {
          // fast GELU: v*sigmoid(1.5957691(v + 0.044715 v^3)); |err| < 0.003
          float z = 1.5957691216f * v * (1.0f + 0.044715f * v * v);
          float gl = v / (1.0f + __expf(-z));
          outh[(size_t)row * 4096 + col] = (_Float16)gl;
        }
      }
    }
  }
}

// ---------------------------------------------------------------------------
// MFMA flash attention, balanced + swizzled (unchanged from round 5).
// Block (pr, bh): q-tiles pr then 31-pr -> exactly 33 key-tile units/block.
// S^T phase: wave w owns keys w*16..+15 for all 64 q-rows; PV phase: wave w
// owns q-rows w*16..+15. K/V LDS XOR-swizzled at load time. grid = (16, B*H).
// ---------------------------------------------------------------------------
__global__ __launch_bounds__(256) void attn_kernel(
    const _Float16* __restrict__ q, const _Float16* __restrict__ k,
    const _Float16* __restrict__ vt, _Float16* __restrict__ ctx) {
  __shared__ __align__(16) _Float16 Ks[2][64 * 64];  // [key][d], swizzled cols
  __shared__ __align__(16) _Float16 Vs[2][64 * 64];  // [d][key], swizzled cols
  __shared__ __align__(16) _Float16 Ps[64 * 72];     // shared P[qrow][key], padded
  __shared__ float Lpart[4][64];                     // per-wave row-sum partials
  const int tid = threadIdx.x;
  const int w = tid >> 6, lane = tid & 63;
  const int l15 = lane & 15, q8 = lane >> 4;
  const int bh = blockIdx.y;
  const int pr = blockIdx.x;  // 0..15
  const size_t base = (size_t)bh * SEQT * HDIM;  // same for q, k, vt

  const _Float16* gk0[2]; const _Float16* gv0[2]; int ldsc[2];
#pragma unroll
  for (int i = 0; i < 2; ++i) {
    int c = i * 256 + w * 64 + lane;
    int r = c >> 3, gc = ((c & 7) ^ (r & 7)) * 8;
    gk0[i] = k + base + (size_t)r * HDIM + gc;
    gv0[i] = vt + base + (size_t)r * SEQT + gc;
    ldsc[i] = c * 8;
  }
  auto stage = [&](int kt, int buf) {
#pragma unroll
    for (int i = 0; i < 2; ++i) {
      llds16(gk0[i] + (size_t)kt * (64 * HDIM), &Ks[buf][ldsc[i]]);
      llds16(gv0[i] + kt * 64, &Vs[buf][ldsc[i]]);
    }
  };

  const int rswA = (l15 & 7);
  const int cs0 = (q8 ^ rswA) * 8;
  const int cs1 = ((4 + q8) ^ rswA) * 8;

  int s = 0;
  stage(0, 0);
  __syncthreads();
  for (int ph = 0; ph < 2; ++ph) {
    const int qtile = ph ? 31 - pr : pr;
    const int ntile = qtile + 1;
    half8 bq[4][2];
#pragma unroll
    for (int nt = 0; nt < 4; ++nt) {
      const half8* qp = (const half8*)(q + base + (size_t)(qtile * 64 + nt * 16 + l15) * HDIM);
      bq[nt][0] = qp[q8];
      bq[nt][1] = qp[4 + q8];
    }
    floatx4 acc[4];
#pragma unroll
    for (int j = 0; j < 4; ++j) acc[j] = (floatx4){0.f, 0.f, 0.f, 0.f};
    float lsum[4] = {0.f, 0.f, 0.f, 0.f};

    for (int jt = 0; jt < ntile; ++jt, ++s) {
      const int buf = s & 1;
      if (s + 1 < 33) {
        int sn = s + 1;
        int nkt = (sn <= pr) ? sn : sn - (pr + 1);
        stage(nkt, buf ^ 1);
      }
      half8 ak0 = *(const half8*)&Ks[buf][(w * 16 + l15) * 64 + cs0];
      half8 ak1 = *(const half8*)&Ks[buf][(w * 16 + l15) * 64 + cs1];
      floatx4 sv[4];
#pragma unroll
      for (int nt = 0; nt < 4; ++nt) {
        sv[nt] = __builtin_amdgcn_mfma_f32_16x16x32_f16(ak0, bq[nt][0],
                                                        (floatx4){0.f, 0.f, 0.f, 0.f}, 0, 0, 0);
        sv[nt] = __builtin_amdgcn_mfma_f32_16x16x32_f16(ak1, bq[nt][1], sv[nt], 0, 0, 0);
      }
      const bool diag = (jt == ntile - 1);
#pragma unroll
      for (int nt = 0; nt < 4; ++nt) {
        half4v phv;
#pragma unroll
        for (int r = 0; r < 4; ++r) {
          float p = __expf(sv[nt][r] * 0.125f);
          if (diag) {
            p = (w * 16 + q8 * 4 + r <= nt * 16 + l15) ? p : 0.f;
          }
          lsum[nt] += p;
          phv[r] = (_Float16)p;
        }
        *(half4v*)&Ps[(nt * 16 + l15) * 72 + w * 16 + q8 * 4] = phv;
      }
      __syncthreads();
      half8 ap0 = *(const half8*)&Ps[(w * 16 + l15) * 72 + q8 * 8];
      half8 ap1 = *(const half8*)&Ps[(w * 16 + l15) * 72 + 32 + q8 * 8];
#pragma unroll
      for (int ntd = 0; ntd < 4; ++ntd) {
        half8 bv0 = *(const half8*)&Vs[buf][(ntd * 16 + l15) * 64 + cs0];
        half8 bv1 = *(const half8*)&Vs[buf][(ntd * 16 + l15) * 64 + cs1];
        acc[ntd] = __builtin_amdgcn_mfma_f32_16x16x32_f16(ap0, bv0, acc[ntd], 0, 0, 0);
        acc[ntd] = __builtin_amdgcn_mfma_f32_16x16x32_f16(ap1, bv1, acc[ntd], 0, 0, 0);
      }
      __syncthreads();
    }

#pragma unroll
    for (int nt = 0; nt < 4; ++nt) {
      lsum[nt] += __shfl_xor(lsum[nt], 16);
      lsum[nt] += __shfl_xor(lsum[nt], 32);
      if (q8 == 0) Lpart[w][nt * 16 + l15] = lsum[nt];
    }
    __syncthreads();
    const int b = bh >> 4, h = bh & 15;
#pragma unroll
    for (int r = 0; r < 4; ++r) {
      int qr = w * 16 + q8 * 4 + r;
      float inv = 1.0f / (Lpart[0][qr] + Lpart[1][qr] + Lpart[2][qr] + Lpart[3][qr]);
      int tg = qtile * 64 + qr;
      _Float16* op = ctx + ((size_t)(b * SEQT + tg)) * DMODEL + h * HDIM;
#pragma unroll
      for (int ntd = 0; ntd < 4; ++ntd)
        op[ntd * 16 + l15] = (_Float16)(acc[ntd][r] * inv);
    }
  }
}

// ---------------------------------------------------------------------------
// Host launch. Workspace layout (88 MB, aliased over the timeline):
//  [0,24M)   wt      : transposed f16 weights (persistent)
//  [24,32M)  h16     : LN1 out -> reused as ctx16 after QKV GEMM reads it
//  [32,56M)  q,k,vt  : f16; q,k [B,H,T,HD], v transposed [B,H,HD,T]
//                      -> [32,48M) reused as x1 (fp32), [48,56M) as h2 (f16)
//  [56,88M)  mid16   : f16 [4096,4096]
// ---------------------------------------------------------------------------
extern "C" void kernel_launch(void* const* d_in, const int* in_sizes, int n_in,
                              void* d_out, int out_size, void* d_ws, size_t ws_size,
                              hipStream_t stream) {
  (void)in_sizes; (void)n_in; (void)out_size; (void)ws_size;
  const float* x    = (const float*)d_in[0];
  const float* ln1g = (const float*)d_in[1];
  const float* ln1b = (const float*)d_in[2];
  const float* Wq   = (const float*)d_in[3];
  const float* bq   = (const float*)d_in[4];
  const float* Wk   = (const float*)d_in[5];
  const float* bk   = (const float*)d_in[6];
  const float* Wv   = (const float*)d_in[7];
  const float* bv   = (const float*)d_in[8];
  const float* Wo   = (const float*)d_in[9];
  const float* bo   = (const float*)d_in[10];
  const float* ln2g = (const float*)d_in[11];
  const float* ln2b = (const float*)d_in[12];
  const float* W1   = (const float*)d_in[13];
  const float* b1   = (const float*)d_in[14];
  const float* W2   = (const float*)d_in[15];
  const float* b2   = (const float*)d_in[16];
  float* out = (float*)d_out;

  char* ws = (char*)d_ws;
  _Float16* wt    = (_Float16*)(ws);
  _Float16* h16   = (_Float16*)(ws + ((size_t)24 << 20));
  _Float16* qkv   = (_Float16*)(ws + ((size_t)32 << 20));
  _Float16* ctx16 = (_Float16*)(ws + ((size_t)24 << 20));  // reuse h16
  float*    x1    = (float*)   (ws + ((size_t)32 << 20));  // reuse q,k
  _Float16* h2    = (_Float16*)(ws + ((size_t)48 << 20));  // reuse vt
  _Float16* mid   = (_Float16*)(ws + ((size_t)56 << 20));

  const size_t QKV1 = (size_t)NTOK * DMODEL;  // 4M elements per matrix

  wtrans_kernel<<<12288, 256, 0, stream>>>(Wq, Wk, Wv, Wo, W1, W2, wt);
  ln_kernel<<<NTOK, 256, 0, stream>>>(x, ln1g, ln1b, h16);
  gemm_kernel<0><<<dim3(32, 24), 320, 0, stream>>>(
      h16, wt, 1024, bq, bk, bv, nullptr, nullptr, qkv);
  attn_kernel<<<dim3(16, 32), 256, 0, stream>>>(
      qkv, qkv + QKV1, qkv + 2 * QKV1, ctx16);
  gemm_kernel<1><<<dim3(32, 16), 320, 0, stream>>>(
      ctx16, wt + (size_t)3 * 1024 * 1024, 1024, bo, nullptr, nullptr, x, x1, nullptr);
  ln_kernel<<<NTOK, 256, 0, stream>>>(x1, ln2g, ln2b, h2);
  gemm_kernel<2><<<dim3(32, 32), 320, 0, stream>>>(
      h2, wt + (size_t)4 * 1024 * 1024, 1024, b1, nullptr, nullptr, nullptr, nullptr, mid);
  gemm_kernel<1><<<dim3(32, 16), 320, 0, stream>>>(
      mid, wt + (size_t)8 * 1024 * 1024, 4096, b2, nullptr, nullptr, x1, out, nullptr);
}

// Round 7
// 380.992 us; speedup vs baseline: 1.0469x; 1.0469x over previous
//
#include <hip/hip_runtime.h>
#include <math.h>

// ---------------------------------------------------------------------------
// TransformerBlock: B=2, T=2048, D=1024, H=16, HD=64, pre-LN, causal attn, GELU
// Round 7: GEMM K-loop with RAW s_barrier (no implicit vmcnt(0) drain) +
// fine-grained s_waitcnt vmcnt(2*IPW) + 4-slot LDS ring, prefetch depth 2.
// Loads stay in flight across barriers (AITER/hipBLASLt pattern). All waves
// stage + compute (round-6 producer/consumer reverted: flag handshake cost
// replaced the drain it removed). Uniform 128x64 tiles, 3 blocks/CU.
// Attention/LN unchanged from round 5.
// ---------------------------------------------------------------------------

typedef _Float16 half8 __attribute__((ext_vector_type(8)));
typedef _Float16 half4v __attribute__((ext_vector_type(4)));
typedef float floatx4 __attribute__((ext_vector_type(4)));

#define DMODEL 1024
#define SEQT   2048
#define NTOK   4096   // B*T
#define NHEAD  16
#define HDIM   64

// Async global->LDS, 16B/lane. LDS dest = wave-uniform base + lane*16 [m104].
__device__ __forceinline__ void llds16(const _Float16* g, _Float16* l) {
  __builtin_amdgcn_global_load_lds(
      (const __attribute__((address_space(1))) void*)g,
      (__attribute__((address_space(3))) void*)l, 16, 0, 0);
}

// s_waitcnt immediate (gfx9): vmcnt[3:0]|[15:14], expcnt[6:4]=7(off),
// lgkmcnt[11:8]=15(off)
#define WAITCNT_VM(n)  (((n) & 15) | (((n) >> 4) << 14) | 0x0F70)

// ---------------------------------------------------------------------------
// Weight convert+transpose: fp32 [K,N] -> f16 [N,K].
// wt layout (elements): Wq^T @0, Wk^T @1M, Wv^T @2M, Wo^T @3M, W1^T @4M (4096x1024),
//                       W2^T @8M (1024x4096). Total 12M halves = 24MB.
// ---------------------------------------------------------------------------
__global__ __launch_bounds__(256) void wtrans_kernel(
    const float* __restrict__ Wq, const float* __restrict__ Wk,
    const float* __restrict__ Wv, const float* __restrict__ Wo,
    const float* __restrict__ W1, const float* __restrict__ W2,
    _Float16* __restrict__ wt_base) {
  __shared__ float tilebuf[32][33];
  int id = blockIdx.x;
  const float* src; _Float16* dst; int K, N, t;
  if (id < 4096) {
    int s = id >> 10;
    src = (s == 0) ? Wq : (s == 1) ? Wk : (s == 2) ? Wv : Wo;
    dst = wt_base + (size_t)s * (1024 * 1024);
    K = 1024; N = 1024; t = id & 1023;
  } else if (id < 8192) {
    src = W1; dst = wt_base + (size_t)4 * 1024 * 1024; K = 1024; N = 4096; t = id - 4096;
  } else {
    src = W2; dst = wt_base + (size_t)8 * 1024 * 1024; K = 4096; N = 1024; t = id - 8192;
  }
  int tilesN = N >> 5;
  int tk = t / tilesN, tn = t % tilesN;
  int c = threadIdx.x & 31, r0 = threadIdx.x >> 5;
#pragma unroll
  for (int i = 0; i < 4; ++i) {
    int r = r0 + i * 8;
    tilebuf[r][c] = src[(size_t)(tk * 32 + r) * N + tn * 32 + c];
  }
  __syncthreads();
#pragma unroll
  for (int i = 0; i < 4; ++i) {
    int r = r0 + i * 8;
    dst[(size_t)(tn * 32 + r) * K + tk * 32 + c] = (_Float16)tilebuf[c][r];
  }
}

// ---------------------------------------------------------------------------
// LayerNorm: fp32 in -> f16 out. One row (D=1024) per 256-thread block.
// ---------------------------------------------------------------------------
__global__ __launch_bounds__(256) void ln_kernel(
    const float* __restrict__ x, const float* __restrict__ g,
    const float* __restrict__ b, _Float16* __restrict__ out) {
  int row = blockIdx.x;
  int t = threadIdx.x;
  const float4 xv = ((const float4*)(x + (size_t)row * DMODEL))[t];
  float s = xv.x + xv.y + xv.z + xv.w;
  float s2 = xv.x * xv.x + xv.y * xv.y + xv.z * xv.z + xv.w * xv.w;
#pragma unroll
  for (int off = 32; off; off >>= 1) {
    s += __shfl_down(s, off);
    s2 += __shfl_down(s2, off);
  }
  __shared__ float red[8];
  int wid = t >> 6;
  if ((t & 63) == 0) { red[wid] = s; red[wid + 4] = s2; }
  __syncthreads();
  s = red[0] + red[1] + red[2] + red[3];
  s2 = red[4] + red[5] + red[6] + red[7];
  float mu = s * (1.0f / DMODEL);
  float var = s2 * (1.0f / DMODEL) - mu * mu;
  float rstd = rsqrtf(var + 1e-5f);
  const float4 gv = ((const float4*)g)[t];
  const float4 bv = ((const float4*)b)[t];
  half4v o;
  o[0] = (_Float16)((xv.x - mu) * rstd * gv.x + bv.x);
  o[1] = (_Float16)((xv.y - mu) * rstd * gv.y + bv.y);
  o[2] = (_Float16)((xv.z - mu) * rstd * gv.z + bv.z);
  o[3] = (_Float16)((xv.w - mu) * rstd * gv.w + bv.w);
  *(half4v*)(out + (size_t)row * DMODEL + t * 4) = o;
}

// ---------------------------------------------------------------------------
// f16 MFMA GEMM: C[4096, N] = A[4096,K] @ B (B as Bt[N,K] f16).
// Tile 128x64x32; 4 waves, wave w = rows w*32..+31 x all 64 cols (2x4 mfma).
// 4-slot LDS ring, prefetch depth 2; raw s_barrier + vmcnt(2*IPW) so loads
// stay in flight across barriers. IPW = 3 staging insts/wave/tile.
// MODE 0: QKV fused; q,k scatter [B,H,T,HD]; v scatters TRANSPOSED [B,H,HD,T]
// MODE 1: bias + residual(fp32) add; fp32 output, row stride 1024
// MODE 2: bias + fast GELU; f16 output, row stride 4096
// ---------------------------------------------------------------------------
template <int MODE>
__global__ __launch_bounds__(256) void gemm_kernel(
    const _Float16* __restrict__ A, const _Float16* __restrict__ Bt0, int K,
    const float* __restrict__ bias0, const float* __restrict__ bias1,
    const float* __restrict__ bias2, const float* __restrict__ res,
    float* __restrict__ outf, _Float16* __restrict__ outh) {
  __shared__ __align__(16) _Float16 As[4][128 * 32];  // 32 KB
  __shared__ __align__(16) _Float16 Bs[4][64 * 32];   // 16 KB
  const int tid = threadIdx.x;
  const int w = tid >> 6, lane = tid & 63;
  const int m0 = blockIdx.x * 128;
  const _Float16* Bt;
  const float* bias;
  _Float16* outh_sel = outh;
  int n0, sel = 0;
  if (MODE == 0) {
    sel = blockIdx.y >> 4;
    n0 = (blockIdx.y & 15) * 64;
    Bt = Bt0 + (size_t)sel * (1024 * 1024);
    bias = (sel == 0) ? bias0 : (sel == 1) ? bias1 : bias2;
    outh_sel = outh + (size_t)sel * ((size_t)NTOK * DMODEL);
  } else {
    n0 = blockIdx.y * 64;
    Bt = Bt0;
    bias = bias0;
  }
  const int l15 = lane & 15, q8 = lane >> 4;
  const int wrow = w * 32;

  // Per-lane staging pointers (A: 2 chunks/lane, B: 1 chunk/lane) + LDS bases.
  const _Float16* gA[2]; int ldsA[2];
  const _Float16* gB; int ldsB;
#pragma unroll
  for (int i = 0; i < 2; ++i) {
    int c0 = i * 256 + w * 64;       // wave-uniform chunk base
    int idx = c0 + lane;
    int m = idx >> 2, kq = (idx & 3) * 8;
    gA[i] = A + (size_t)(m0 + m) * K + kq;
    ldsA[i] = c0 * 8;
  }
  {
    int c0 = w * 64;
    int idx = c0 + lane;
    int m = idx >> 2, kq = (idx & 3) * 8;
    gB = Bt + (size_t)(n0 + m) * K + kq;
    ldsB = c0 * 8;
  }
  auto stage = [&](int slot) {  // tiles staged in monotonic order; bump +=32
    llds16(gA[0], &As[slot][ldsA[0]]); gA[0] += 32;
    llds16(gA[1], &As[slot][ldsA[1]]); gA[1] += 32;
    llds16(gB, &Bs[slot][ldsB]);       gB += 32;
  };

  floatx4 acc[2][4];
#pragma unroll
  for (int i = 0; i < 2; ++i)
#pragma unroll
    for (int j = 0; j < 4; ++j) acc[i][j] = (floatx4){0.f, 0.f, 0.f, 0.f};

  auto compute = [&](int slot) {
    const _Float16* as = &As[slot][0];
    const _Float16* bs = &Bs[slot][0];
    half8 af[2], bf[4];
#pragma unroll
    for (int i = 0; i < 2; ++i)
      af[i] = *(const half8*)&as[(wrow + i * 16 + l15) * 32 + q8 * 8];
#pragma unroll
    for (int j = 0; j < 4; ++j)
      bf[j] = *(const half8*)&bs[(j * 16 + l15) * 32 + q8 * 8];
#pragma unroll
    for (int i = 0; i < 2; ++i)
#pragma unroll
      for (int j = 0; j < 4; ++j)
        acc[i][j] = __builtin_amdgcn_mfma_f32_16x16x32_f16(af[i], bf[j], acc[i][j], 0, 0, 0);
  };

  const int nk = K >> 5;  // >= 32 always
  stage(0);
  stage(1);
  // Main loop: stage t+2, wait own tile-t loads (2 tiles = 6 insts in flight),
  // RAW barrier (no drain), compute t. Ring R=4 >= D+2 keeps slot reuse safe.
  for (int t = 0; t < nk - 2; ++t) {
    stage((t + 2) & 3);
    __builtin_amdgcn_s_waitcnt(WAITCNT_VM(6));
    asm volatile("s_barrier" ::: "memory");
    compute(t & 3);
  }
  __builtin_amdgcn_s_waitcnt(WAITCNT_VM(3));
  asm volatile("s_barrier" ::: "memory");
  compute((nk - 2) & 3);
  __builtin_amdgcn_s_waitcnt(WAITCNT_VM(0));
  asm volatile("s_barrier" ::: "memory");
  compute((nk - 1) & 3);

  // Epilogue. C/D layout: col = lane&15, row = (lane>>4)*4 + reg   [m89/m91]
#pragma unroll
  for (int i = 0; i < 2; ++i) {
    int rowb = m0 + wrow + i * 16 + q8 * 4;
#pragma unroll
    for (int j = 0; j < 4; ++j) {
      int col = n0 + j * 16 + l15;
      float bval = bias[col];
#pragma unroll
      for (int r = 0; r < 4; ++r) {
        int row = rowb + r;
        float v = acc[i][j][r] + bval;
        if (MODE == 0) {
          int bb = row >> 11, tt = row & 2047;
          int hh = col >> 6, hd = col & 63;
          if (sel == 2)  // V transposed: [B,H,HD,T] so attention PV needs no LDS transpose
            outh_sel[((size_t)(bb * NHEAD + hh) * HDIM + hd) * SEQT + tt] = (_Float16)v;
          else
            outh_sel[((size_t)(bb * NHEAD + hh) * SEQT + tt) * HDIM + hd] = (_Float16)v;
        } else if (MODE == 1) {
          v += res[(size_t)row * 1024 + col];
          outf[(size_t)row * 1024 + col] = v;
        } else {
          // fast GELU: v*sigmoid(1.5957691(v + 0.044715 v^3)); |err| < 0.003
          float z = 1.5957691216f * v * (1.0f + 0.044715f * v * v);
          float gl = v / (1.0f + __expf(-z));
          outh[(size_t)row * 4096 + col] = (_Float16)gl;
        }
      }
    }
  }
}

// ---------------------------------------------------------------------------
// MFMA flash attention, balanced + swizzled (unchanged from round 5).
// Block (pr, bh): q-tiles pr then 31-pr -> exactly 33 key-tile units/block.
// S^T phase: wave w owns keys w*16..+15 for all 64 q-rows; PV phase: wave w
// owns q-rows w*16..+15. K/V LDS XOR-swizzled at load time. grid = (16, B*H).
// ---------------------------------------------------------------------------
__global__ __launch_bounds__(256) void attn_kernel(
    const _Float16* __restrict__ q, const _Float16* __restrict__ k,
    const _Float16* __restrict__ vt, _Float16* __restrict__ ctx) {
  __shared__ __align__(16) _Float16 Ks[2][64 * 64];  // [key][d], swizzled cols
  __shared__ __align__(16) _Float16 Vs[2][64 * 64];  // [d][key], swizzled cols
  __shared__ __align__(16) _Float16 Ps[64 * 72];     // shared P[qrow][key], padded
  __shared__ float Lpart[4][64];                     // per-wave row-sum partials
  const int tid = threadIdx.x;
  const int w = tid >> 6, lane = tid & 63;
  const int l15 = lane & 15, q8 = lane >> 4;
  const int bh = blockIdx.y;
  const int pr = blockIdx.x;  // 0..15
  const size_t base = (size_t)bh * SEQT * HDIM;  // same for q, k, vt

  const _Float16* gk0[2]; const _Float16* gv0[2]; int ldsc[2];
#pragma unroll
  for (int i = 0; i < 2; ++i) {
    int c = i * 256 + w * 64 + lane;
    int r = c >> 3, gc = ((c & 7) ^ (r & 7)) * 8;
    gk0[i] = k + base + (size_t)r * HDIM + gc;
    gv0[i] = vt + base + (size_t)r * SEQT + gc;
    ldsc[i] = c * 8;
  }
  auto stage = [&](int kt, int buf) {
#pragma unroll
    for (int i = 0; i < 2; ++i) {
      llds16(gk0[i] + (size_t)kt * (64 * HDIM), &Ks[buf][ldsc[i]]);
      llds16(gv0[i] + kt * 64, &Vs[buf][ldsc[i]]);
    }
  };

  const int rswA = (l15 & 7);
  const int cs0 = (q8 ^ rswA) * 8;
  const int cs1 = ((4 + q8) ^ rswA) * 8;

  int s = 0;
  stage(0, 0);
  __syncthreads();
  for (int ph = 0; ph < 2; ++ph) {
    const int qtile = ph ? 31 - pr : pr;
    const int ntile = qtile + 1;
    half8 bq[4][2];
#pragma unroll
    for (int nt = 0; nt < 4; ++nt) {
      const half8* qp = (const half8*)(q + base + (size_t)(qtile * 64 + nt * 16 + l15) * HDIM);
      bq[nt][0] = qp[q8];
      bq[nt][1] = qp[4 + q8];
    }
    floatx4 acc[4];
#pragma unroll
    for (int j = 0; j < 4; ++j) acc[j] = (floatx4){0.f, 0.f, 0.f, 0.f};
    float lsum[4] = {0.f, 0.f, 0.f, 0.f};

    for (int jt = 0; jt < ntile; ++jt, ++s) {
      const int buf = s & 1;
      if (s + 1 < 33) {
        int sn = s + 1;
        int nkt = (sn <= pr) ? sn : sn - (pr + 1);
        stage(nkt, buf ^ 1);
      }
      half8 ak0 = *(const half8*)&Ks[buf][(w * 16 + l15) * 64 + cs0];
      half8 ak1 = *(const half8*)&Ks[buf][(w * 16 + l15) * 64 + cs1];
      floatx4 sv[4];
#pragma unroll
      for (int nt = 0; nt < 4; ++nt) {
        sv[nt] = __builtin_amdgcn_mfma_f32_16x16x32_f16(ak0, bq[nt][0],
                                                        (floatx4){0.f, 0.f, 0.f, 0.f}, 0, 0, 0);
        sv[nt] = __builtin_amdgcn_mfma_f32_16x16x32_f16(ak1, bq[nt][1], sv[nt], 0, 0, 0);
      }
      const bool diag = (jt == ntile - 1);
#pragma unroll
      for (int nt = 0; nt < 4; ++nt) {
        half4v phv;
#pragma unroll
        for (int r = 0; r < 4; ++r) {
          float p = __expf(sv[nt][r] * 0.125f);
          if (diag) {
            p = (w * 16 + q8 * 4 + r <= nt * 16 + l15) ? p : 0.f;
          }
          lsum[nt] += p;
          phv[r] = (_Float16)p;
        }
        *(half4v*)&Ps[(nt * 16 + l15) * 72 + w * 16 + q8 * 4] = phv;
      }
      __syncthreads();
      half8 ap0 = *(const half8*)&Ps[(w * 16 + l15) * 72 + q8 * 8];
      half8 ap1 = *(const half8*)&Ps[(w * 16 + l15) * 72 + 32 + q8 * 8];
#pragma unroll
      for (int ntd = 0; ntd < 4; ++ntd) {
        half8 bv0 = *(const half8*)&Vs[buf][(ntd * 16 + l15) * 64 + cs0];
        half8 bv1 = *(const half8*)&Vs[buf][(ntd * 16 + l15) * 64 + cs1];
        acc[ntd] = __builtin_amdgcn_mfma_f32_16x16x32_f16(ap0, bv0, acc[ntd], 0, 0, 0);
        acc[ntd] = __builtin_amdgcn_mfma_f32_16x16x32_f16(ap1, bv1, acc[ntd], 0, 0, 0);
      }
      __syncthreads();
    }

#pragma unroll
    for (int nt = 0; nt < 4; ++nt) {
      lsum[nt] += __shfl_xor(lsum[nt], 16);
      lsum[nt] += __shfl_xor(lsum[nt], 32);
      if (q8 == 0) Lpart[w][nt * 16 + l15] = lsum[nt];
    }
    __syncthreads();
    const int b = bh >> 4, h = bh & 15;
#pragma unroll
    for (int r = 0; r < 4; ++r) {
      int qr = w * 16 + q8 * 4 + r;
      float inv = 1.0f / (Lpart[0][qr] + Lpart[1][qr] + Lpart[2][qr] + Lpart[3][qr]);
      int tg = qtile * 64 + qr;
      _Float16* op = ctx + ((size_t)(b * SEQT + tg)) * DMODEL + h * HDIM;
#pragma unroll
      for (int ntd = 0; ntd < 4; ++ntd)
        op[ntd * 16 + l15] = (_Float16)(acc[ntd][r] * inv);
    }
  }
}

// ---------------------------------------------------------------------------
// Host launch. Workspace layout (88 MB, aliased over the timeline):
//  [0,24M)   wt      : transposed f16 weights (persistent)
//  [24,32M)  h16     : LN1 out -> reused as ctx16 after QKV GEMM reads it
//  [32,56M)  q,k,vt  : f16; q,k [B,H,T,HD], v transposed [B,H,HD,T]
//                      -> [32,48M) reused as x1 (fp32), [48,56M) as h2 (f16)
//  [56,88M)  mid16   : f16 [4096,4096]
// ---------------------------------------------------------------------------
extern "C" void kernel_launch(void* const* d_in, const int* in_sizes, int n_in,
                              void* d_out, int out_size, void* d_ws, size_t ws_size,
                              hipStream_t stream) {
  (void)in_sizes; (void)n_in; (void)out_size; (void)ws_size;
  const float* x    = (const float*)d_in[0];
  const float* ln1g = (const float*)d_in[1];
  const float* ln1b = (const float*)d_in[2];
  const float* Wq   = (const float*)d_in[3];
  const float* bq   = (const float*)d_in[4];
  const float* Wk   = (const float*)d_in[5];
  const float* bk   = (const float*)d_in[6];
  const float* Wv   = (const float*)d_in[7];
  const float* bv   = (const float*)d_in[8];
  const float* Wo   = (const float*)d_in[9];
  const float* bo   = (const float*)d_in[10];
  const float* ln2g = (const float*)d_in[11];
  const float* ln2b = (const float*)d_in[12];
  const float* W1   = (const float*)d_in[13];
  const float* b1   = (const float*)d_in[14];
  const float* W2   = (const float*)d_in[15];
  const float* b2   = (const float*)d_in[16];
  float* out = (float*)d_out;

  char* ws = (char*)d_ws;
  _Float16* wt    = (_Float16*)(ws);
  _Float16* h16   = (_Float16*)(ws + ((size_t)24 << 20));
  _Float16* qkv   = (_Float16*)(ws + ((size_t)32 << 20));
  _Float16* ctx16 = (_Float16*)(ws + ((size_t)24 << 20));  // reuse h16
  float*    x1    = (float*)   (ws + ((size_t)32 << 20));  // reuse q,k
  _Float16* h2    = (_Float16*)(ws + ((size_t)48 << 20));  // reuse vt
  _Float16* mid   = (_Float16*)(ws + ((size_t)56 << 20));

  const size_t QKV1 = (size_t)NTOK * DMODEL;  // 4M elements per matrix

  wtrans_kernel<<<12288, 256, 0, stream>>>(Wq, Wk, Wv, Wo, W1, W2, wt);
  ln_kernel<<<NTOK, 256, 0, stream>>>(x, ln1g, ln1b, h16);
  gemm_kernel<0><<<dim3(32, 48), 256, 0, stream>>>(
      h16, wt, 1024, bq, bk, bv, nullptr, nullptr, qkv);
  attn_kernel<<<dim3(16, 32), 256, 0, stream>>>(
      qkv, qkv + QKV1, qkv + 2 * QKV1, ctx16);
  gemm_kernel<1><<<dim3(32, 16), 256, 0, stream>>>(
      ctx16, wt + (size_t)3 * 1024 * 1024, 1024, bo, nullptr, nullptr, x, x1, nullptr);
  ln_kernel<<<NTOK, 256, 0, stream>>>(x1, ln2g, ln2b, h2);
  gemm_kernel<2><<<dim3(32, 64), 256, 0, stream>>>(
      h2, wt + (size_t)4 * 1024 * 1024, 1024, b1, nullptr, nullptr, nullptr, nullptr, mid);
  gemm_kernel<1><<<dim3(32, 16), 256, 0, stream>>>(
      mid, wt + (size_t)8 * 1024 * 1024, 4096, b2, nullptr, nullptr, x1, out, nullptr);
}